// Round 3
// baseline (114.257 us; speedup 1.0000x reference)
//
#include <hip/hip_runtime.h>
#include <math.h>

constexpr int NBINS = 1025;              // 2048/2 + 1
constexpr int NROWS = 128 * 192;         // B * P
constexpr int RPB   = 16;                // rows per block
constexpr int NBLK  = NROWS / RPB;       // 1536 blocks = full residency
constexpr int STPB  = RPB * NBINS / 4;   // 4100 dwordx4 stores per block

// Single-instruction RNE bf16 pack: LOW half = im, HIGH half = re (R3/R4 layout).
__device__ inline unsigned int pack_bf16(float im, float re) {
    unsigned int u;
    asm("v_cvt_pk_bf16_f32 %0, %1, %2" : "=v"(u) : "v"(im), "v"(re));
    return u;
}

// R9 LDS swizzle: flat-ownership tab reads are lane-stride 32 B (4 bins/lane)
// -> bank bits [6:5] only -> 16-way conflict. XOR byte bits [4:3] with bits
// [8:7] (bijective, 8B-align preserved): 16 consecutive lanes -> 16 distinct
// bank-pairs -> b64 reads at the conflict-free floor. Applied on BOTH the
// prologue ds_write and the loop ds_read (both-sides rule).
__device__ inline int swz(int b) { return b ^ ((b >> 4) & 0x18); }

// H(theta) = (d + i*g1*s)/(d + i*g2*s), theta = pi*k/1024, h = theta/2.
// Product form (cancellation-safe near resonance):
//   dp = (sh - st)(sh + st), sh = sin(w0/2), st = sin(h); s = sin(theta)
//   re = (dp^2 + (a^2/4) s^2) / (dp^2 + (g2^2/4) s^2)
//   im = ((g1-g2)/2)*s*dp     / (dp^2 + (g2^2/4) s^2)
// Row consts P = (sh, alpha^2/4, g2^2/4, (g1-g2)/2).
//
// R9 store restructure: block b owns flat dwords [16400b, 16400(b+1)) =
// rows 16b..16b+15 exactly (16*1025 = 16400). Base byte 65600b % 16 == 0,
// so ALL output traffic is aligned global_store_dwordx4 (4100/block), half
// the store instructions of the R7 parity-paired dwordx2 scheme. Row/bin of
// each store tracked incrementally: o += 1024 dwords/iter -> k += 1024,
// single wrap at 1025. A store straddles a row boundary iff k > 1021
// (<=1 lane/wave, rare slow path).
__global__ __launch_bounds__(256) void eq_kernel(
    const float* __restrict__ center,
    const float* __restrict__ gain,
    const float* __restrict__ q,
    unsigned int* __restrict__ out)
{
    __shared__ float2 tab[NBINS];        // swizzled placement: (sin h, sin theta)
    __shared__ float4 rp[RPB];           // (sh, A2, G2, GD) per row

    const int tid  = threadIdx.x;
    const int row0 = blockIdx.x * RPB;

    if (tid < RPB) {
        const int row = row0 + tid;
        float w0 = 1.4247585730565955e-4f * center[row];   // 2*pi/44100
        float sh, ch;
        sincosf(0.5f * w0, &sh, &ch);                      // sin/cos of w0/2
        float A = exp2f(0.08304820237218406f * gain[row]); // 10^(gain/40)
        float alpha = sh * ch / q[row];                    // sin(w0)/(2q)
        float g2 = alpha / A;
        float gd = alpha * A - g2;                         // g1 - g2
        rp[tid] = make_float4(sh, 0.25f * alpha * alpha, 0.25f * g2 * g2, 0.5f * gd);
    }
    char* tb = (char*)tab;
    for (int k = tid; k < NBINS; k += 256) {
        float st, ct;
        sincosf((float)k * 1.5339807878856412e-3f, &st, &ct); // h = pi*k/2048
        *(float2*)(tb + swz(8 * k)) = make_float2(st, 2.0f * st * ct);
    }
    __syncthreads();

    uint4* __restrict__ ob = (uint4*)(out + (size_t)row0 * NBINS);
    int k = 4 * tid;                     // bin of first elem (4*255=1020 < 1025)
    int r = 0;                           // local row of first elem
    for (int si = tid; si < STPB; si += 256) {
        uint4 res;
        unsigned int* rw = (unsigned int*)&res;
        if (k <= NBINS - 4) {            // fast path: all 4 bins in row r
            const float4 P = rp[r];
            #pragma unroll
            for (int j = 0; j < 4; ++j) {
                const float2 t = *(const float2*)(tb + swz(8 * (k + j)));
                float dp = (P.x - t.x) * (P.x + t.x);
                float D2 = dp * dp, S2 = t.y * t.y;
                float inv = __builtin_amdgcn_rcpf(fmaf(P.z, S2, D2));
                rw[j] = pack_bf16(P.w * t.y * dp * inv,
                                  fmaf(P.y, S2, D2) * inv);
            }
        } else {                         // store straddles a row boundary
            #pragma unroll
            for (int j = 0; j < 4; ++j) {
                int kj = k + j, rj = r;
                if (kj >= NBINS) { kj -= NBINS; ++rj; }
                const float4 P = rp[rj];
                const float2 t = *(const float2*)(tb + swz(8 * kj));
                float dp = (P.x - t.x) * (P.x + t.x);
                float D2 = dp * dp, S2 = t.y * t.y;
                float inv = __builtin_amdgcn_rcpf(fmaf(P.z, S2, D2));
                rw[j] = pack_bf16(P.w * t.y * dp * inv,
                                  fmaf(P.y, S2, D2) * inv);
            }
        }
        ob[si] = res;                    // aligned 16B store, 1 KB/wave
        k += 1024;
        if (k >= NBINS) { k -= NBINS; ++r; }
    }
}

extern "C" void kernel_launch(void* const* d_in, const int* in_sizes, int n_in,
                              void* d_out, int out_size, void* d_ws, size_t ws_size,
                              hipStream_t stream) {
    const float* center = (const float*)d_in[0];
    const float* gain   = (const float*)d_in[1];
    const float* q      = (const float*)d_in[2];
    eq_kernel<<<NBLK, 256, 0, stream>>>(center, gain, q, (unsigned int*)d_out);
}